// Round 9
// baseline (918.741 us; speedup 1.0000x reference)
//
#include <hip/hip_runtime.h>
#include <stdint.h>

constexpr int NB = 64;     // batch
constexpr int NT = 2048;   // time steps
constexpr int ND = 512;    // feature dim
constexpr int NU = 512;    // attention units

typedef float f32x4 __attribute__((ext_vector_type(4)));
typedef float f32x16 __attribute__((ext_vector_type(16)));
typedef short bf16x8 __attribute__((ext_vector_type(8)));

__device__ __forceinline__ unsigned short f2bf(float x) {
  union { float f; unsigned int u; } v; v.f = x;
  unsigned int r = v.u + 0x7FFFu + ((v.u >> 16) & 1u);  // RNE
  return (unsigned short)(r >> 16);
}

__device__ __forceinline__ float fast_tanh(float x) {
  // exact at the tails (exp->0 or inf), ~1e-7 error midrange
  return 1.0f - 2.0f / (__expf(2.0f * x) + 1.0f);
}

// ---------------- K0a: q[b,u] = dh[b,:] @ W1[:,u] + b1[u] + b2[u] ----------------
__global__ __launch_bounds__(512) void qproj_kernel(
    const float* __restrict__ dh, const float* __restrict__ W1,
    const float* __restrict__ b1, const float* __restrict__ b2,
    float* __restrict__ q) {
  int b = blockIdx.x;
  int u = threadIdx.x;
  const float* dr = dh + b * ND;
  float a0 = 0.f, a1 = 0.f, a2 = 0.f, a3 = 0.f;
  for (int k = 0; k < ND; k += 4) {
    a0 = fmaf(dr[k + 0], W1[(size_t)(k + 0) * NU + u], a0);
    a1 = fmaf(dr[k + 1], W1[(size_t)(k + 1) * NU + u], a1);
    a2 = fmaf(dr[k + 2], W1[(size_t)(k + 2) * NU + u], a2);
    a3 = fmaf(dr[k + 3], W1[(size_t)(k + 3) * NU + u], a3);
  }
  q[b * NU + u] = b1[u] + b2[u] + ((a0 + a1) + (a2 + a3));
}

// ---------------- K0b: pack W2 -> bf16 32x32x16 fragment order ----------------
// byte layout: ks*16384 + ntg*1024 + lane*16 ; element j: u = ntg*32 + (lane&31),
// d = ks*16 + (lane>>5)*8 + j.  (Used as the MFMA *A* operand: m=u, k=d.)
__global__ __launch_bounds__(256) void packW2_kernel(
    const float* __restrict__ W2, unsigned short* __restrict__ w2p) {
  int tid = blockIdx.x * 256 + threadIdx.x;  // 0..32767
  int lane = tid & 63;
  int ntg = (tid >> 6) & 15;
  int ks = tid >> 10;
  int col = ntg * 32 + (lane & 31);
  int k0 = ks * 16 + ((lane >> 5) << 3);
  const float* src = W2 + (size_t)k0 * NU + col;
  ushort4 lo, hi;
  lo.x = f2bf(src[0 * NU]); lo.y = f2bf(src[1 * NU]);
  lo.z = f2bf(src[2 * NU]); lo.w = f2bf(src[3 * NU]);
  hi.x = f2bf(src[4 * NU]); hi.y = f2bf(src[5 * NU]);
  hi.z = f2bf(src[6 * NU]); hi.w = f2bf(src[7 * NU]);
  ushort4* dst = (ushort4*)(w2p + (size_t)tid * 8);
  dst[0] = lo; dst[1] = hi;
}

// ---------------- K2: fused logits = tanh(q + enc@W2) @ V  (bV softmax-invariant)
// Operand-swapped (D[u,t] = mfma(W2frag, encfrag)) with 32-row t-tiles:
//   acc = 2 x f32x16 (32 regs, half of R8) -> live set ~83 regs, budget 85
//   at __launch_bounds__(512,6) -> 3 blocks/CU (24 waves): 1.5x concurrency.
// enc tile in column-plane LDS (512B planes, verified-conflict-free family).
// W2 (A-op) streams from L2 via depth-2 named ring, wrapped 32-bit offsets.
__global__ __launch_bounds__(512, 6) void logits_kernel(
    const float* __restrict__ enc, const unsigned short* __restrict__ w2p,
    const float* __restrict__ q, const float* __restrict__ Vw,
    float* __restrict__ logits) {
  __shared__ unsigned short encB[32 * 512];   // 32KB: (kc<<9) | slot(t,kc)<<4
  __shared__ float qV0[NU];                   // q[b,:]
  __shared__ float qV1[NU];                   // V
  __shared__ float red[8][32];

  const int tid = threadIdx.x;
  const int wave = tid >> 6;
  const int lane = tid & 63;
  const int wg = blockIdx.x;                  // 4096 = (b:64) x (tch:64)
  const int b = wg >> 6;
  const char* w2pc = (const char*)w2p;

  // wave-uniform K rotation (desync; SGPR)
  const int rot = __builtin_amdgcn_readfirstlane(wave * 4);

  // W2 (A-operand) depth-2 register ring: this wave's u-tiles {2*wave, 2*wave+1}
  const int bsub = ((2 * wave) * 64 + lane) * 16;
  int voff = rot * 16384 + bsub;
  bf16x8 a0a = *(const bf16x8*)(w2pc + voff);
  bf16x8 a0b = *(const bf16x8*)(w2pc + voff + 1024);
  voff = (voff + 16384) & 0x7FFFF;
  bf16x8 a1a = *(const bf16x8*)(w2pc + voff);
  bf16x8 a1b = *(const bf16x8*)(w2pc + voff + 1024);
  voff = (voff + 16384) & 0x7FFFF;   // -> ks = (rot+2)&31, first refill target

  // stage q/V table (block-uniform)
  qV0[tid] = q[b * NU + tid];
  qV1[tid] = Vw[tid];

  // stage enc tile [32 t x 512 d] f32 -> bf16 column-plane LDS
  // plane kc (8 d-elems), slot = (t ^ kc)&31: writes 2-way-aliased (free), reads clean
  const float4* encBase = (const float4*)(enc + (size_t)wg * 32 * ND);
  char* eB = (char*)encB;
#pragma unroll
  for (int i = 0; i < 4; ++i) {
    int idx8 = i * 512 + tid;     // float8 index: t = idx8>>6, kc = idx8&63
    int t = idx8 >> 6;
    int kc = idx8 & 63;
    float4 v0 = encBase[idx8 * 2];
    float4 v1 = encBase[idx8 * 2 + 1];
    unsigned int p0, p1, p2, p3;
    asm("v_cvt_pk_bf16_f32 %0, %1, %2" : "=v"(p0) : "v"(v0.x), "v"(v0.y));
    asm("v_cvt_pk_bf16_f32 %0, %1, %2" : "=v"(p1) : "v"(v0.z), "v"(v0.w));
    asm("v_cvt_pk_bf16_f32 %0, %1, %2" : "=v"(p2) : "v"(v1.x), "v"(v1.y));
    asm("v_cvt_pk_bf16_f32 %0, %1, %2" : "=v"(p3) : "v"(v1.z), "v"(v1.w));
    uint4 pk; pk.x = p0; pk.y = p1; pk.z = p2; pk.w = p3;
    int waddr = (kc << 9) | ((((t ^ kc) & 31)) << 4);
    *(uint4*)(eB + waddr) = pk;
  }

  f32x16 acc0 = {}, acc1 = {};

  // enc-frag (B-operand) addressing: kc = 2*ks + hi;
  // addr = ((kc<<9) | ((kc&31)<<4)) ^ (t<<4), t = lane&31
  const int hi = lane >> 5;
  const int tsh = (lane & 31) << 4;

  __syncthreads();

#define PHASE(I, AA, AB)                                                           \
  {                                                                                \
    int ks_ = (rot + (I)) & 31;                                                    \
    int kc_ = 2 * ks_ + hi;                                                        \
    int ea_ = ((kc_ << 9) | ((kc_ & 31) << 4)) ^ tsh;                              \
    bf16x8 e0 = *(const bf16x8*)(eB + ea_);                                        \
    __builtin_amdgcn_s_setprio(1);                                                 \
    acc0 = __builtin_amdgcn_mfma_f32_32x32x16_bf16(AA, e0, acc0, 0, 0, 0);         \
    acc1 = __builtin_amdgcn_mfma_f32_32x32x16_bf16(AB, e0, acc1, 0, 0, 0);         \
    __builtin_amdgcn_s_setprio(0);                                                 \
    AA = *(const bf16x8*)(w2pc + voff);                                            \
    AB = *(const bf16x8*)(w2pc + voff + 1024);                                     \
    voff = (voff + 16384) & 0x7FFFF;                                               \
  }
  // tail refills wrap to already-consumed ks: in-bounds, harmless
#pragma unroll
  for (int i = 0; i < 32; i += 2) {
    PHASE(i + 0, a0a, a0b)
    PHASE(i + 1, a1a, a1b)
  }
#undef PHASE

  // epilogue: per-lane u-reduction over D[u,t].
  // t = lane&31; u = wave*64 + 32*tile + (reg&3) + 8*(reg>>2) + 4*hi
  const int hi4 = hi << 2;
  float s = 0.f;
#pragma unroll
  for (int rg = 0; rg < 4; ++rg) {
    int uo = wave * 64 + 8 * rg + hi4;
    float4 qq = *(const float4*)&qV0[uo];
    float4 vv = *(const float4*)&qV1[uo];
    s += fast_tanh(acc0[4 * rg + 0] + qq.x) * vv.x + fast_tanh(acc0[4 * rg + 1] + qq.y) * vv.y
       + fast_tanh(acc0[4 * rg + 2] + qq.z) * vv.z + fast_tanh(acc0[4 * rg + 3] + qq.w) * vv.w;
  }
#pragma unroll
  for (int rg = 0; rg < 4; ++rg) {
    int uo = wave * 64 + 32 + 8 * rg + hi4;
    float4 qq = *(const float4*)&qV0[uo];
    float4 vv = *(const float4*)&qV1[uo];
    s += fast_tanh(acc1[4 * rg + 0] + qq.x) * vv.x + fast_tanh(acc1[4 * rg + 1] + qq.y) * vv.y
       + fast_tanh(acc1[4 * rg + 2] + qq.z) * vv.z + fast_tanh(acc1[4 * rg + 3] + qq.w) * vv.w;
  }
  s += __shfl_xor(s, 32);   // fold the two hi-halves of u
  if (lane < 32) red[wave][lane] = s;
  __syncthreads();
  if (tid < 32) {
    float t = 0.f;
#pragma unroll
    for (int w = 0; w < 8; ++w) t += red[w][tid];
    logits[(size_t)wg * 32 + tid] = t;
  }
}

// ---------------- K3: in-place softmax over T per batch ----------------
__global__ __launch_bounds__(512) void softmax_kernel(float* __restrict__ wts) {
  int b = blockIdx.x;
  int tid = threadIdx.x;
  float4* base = (float4*)(wts + (size_t)b * NT);
  float4 v = base[tid];
  float m = fmaxf(fmaxf(v.x, v.y), fmaxf(v.z, v.w));
#pragma unroll
  for (int d = 1; d < 64; d <<= 1) m = fmaxf(m, __shfl_xor(m, d));
  __shared__ float sm[8];
  __shared__ float ss[8];
  int w = tid >> 6;
  if ((tid & 63) == 0) sm[w] = m;
  __syncthreads();
  float M = sm[0];
#pragma unroll
  for (int i = 1; i < 8; ++i) M = fmaxf(M, sm[i]);
  float e0 = __expf(v.x - M), e1 = __expf(v.y - M), e2 = __expf(v.z - M), e3 = __expf(v.w - M);
  float s = e0 + e1 + e2 + e3;
#pragma unroll
  for (int d = 1; d < 64; d <<= 1) s += __shfl_xor(s, d);
  if ((tid & 63) == 0) ss[w] = s;
  __syncthreads();
  float S = 0.f;
#pragma unroll
  for (int i = 0; i < 8; ++i) S += ss[i];
  float inv = 1.0f / S;
  base[tid] = (float4){e0 * inv, e1 * inv, e2 * inv, e3 * inv};
}

// ---------------- K4: context partials over t-slices (f32, coalesced) ----------------
__global__ __launch_bounds__(512) void ctx_partial_kernel(
    const float* __restrict__ enc, const float* __restrict__ wts,
    float* __restrict__ partials) {
  int bx = blockIdx.x;          // b*16 + slice
  int b = bx >> 4;
  int slice = bx & 15;
  int tid = threadIdx.x;        // d index
  const float* e = enc + ((size_t)b * NT + (size_t)slice * 128) * ND + tid;
  const float* wp = wts + (size_t)b * NT + slice * 128;
  float acc = 0.0f;
#pragma unroll 4
  for (int tt = 0; tt < 128; ++tt) {
    acc = fmaf(wp[tt], e[(size_t)tt * ND], acc);
  }
  partials[(size_t)bx * ND + tid] = acc;
}

__global__ __launch_bounds__(512) void ctx_combine_kernel(
    const float* __restrict__ partials, float* __restrict__ ctx) {
  int b = blockIdx.x;
  int tid = threadIdx.x;
  float s = 0.0f;
#pragma unroll
  for (int i = 0; i < 16; ++i) s += partials[((size_t)b * 16 + i) * ND + tid];
  ctx[(size_t)b * ND + tid] = s;
}

// ---------------- launch ----------------
extern "C" void kernel_launch(void* const* d_in, const int* in_sizes, int n_in,
                              void* d_out, int out_size, void* d_ws, size_t ws_size,
                              hipStream_t stream) {
  const float* dh  = (const float*)d_in[0];
  const float* enc = (const float*)d_in[1];
  const float* W1  = (const float*)d_in[2];
  const float* b1  = (const float*)d_in[3];
  const float* W2  = (const float*)d_in[4];
  const float* b2  = (const float*)d_in[5];
  const float* Vw  = (const float*)d_in[6];
  // d_in[7] = bV: softmax is shift-invariant and logits are not an output -> unused

  // workspace layout
  float* q            = (float*)d_ws;                                  // 128KB
  unsigned short* w2p = (unsigned short*)((char*)d_ws + 131072);       // 512KB packed bf16
  float* partials     = (float*)((char*)d_ws + 655360);                // 2MB

  float* ctx = (float*)d_out;                 // [64,512]
  float* wts = (float*)d_out + NB * ND;       // [64,2048] (logits, then softmaxed in place)

  qproj_kernel<<<NB, 512, 0, stream>>>(dh, W1, b1, b2, q);
  packW2_kernel<<<128, 256, 0, stream>>>(W2, w2p);
  logits_kernel<<<NB * (NT / 32), 512, 0, stream>>>(enc, w2p, q, Vw, wts);
  softmax_kernel<<<NB, 512, 0, stream>>>(wts);
  ctx_partial_kernel<<<NB * 16, 512, 0, stream>>>(enc, wts, partials);
  ctx_combine_kernel<<<NB, 512, 0, stream>>>(partials, ctx);
}

// Round 10
// 176.635 us; speedup vs baseline: 5.2014x; 5.2014x over previous
//
#include <hip/hip_runtime.h>
#include <stdint.h>

constexpr int NB = 64;     // batch
constexpr int NT = 2048;   // time steps
constexpr int ND = 512;    // feature dim
constexpr int NU = 512;    // attention units

typedef float f32x4 __attribute__((ext_vector_type(4)));
typedef float f32x16 __attribute__((ext_vector_type(16)));
typedef short bf16x8 __attribute__((ext_vector_type(8)));

__device__ __forceinline__ unsigned short f2bf(float x) {
  union { float f; unsigned int u; } v; v.f = x;
  unsigned int r = v.u + 0x7FFFu + ((v.u >> 16) & 1u);  // RNE
  return (unsigned short)(r >> 16);
}

__device__ __forceinline__ float fast_tanh(float x) {
  // exact at the tails (exp->0 or inf), ~1e-7 error midrange
  return 1.0f - 2.0f / (__expf(2.0f * x) + 1.0f);
}

// ---------------- K0a: q[b,u] = dh[b,:] @ W1[:,u] + b1[u] + b2[u] ----------------
__global__ __launch_bounds__(512) void qproj_kernel(
    const float* __restrict__ dh, const float* __restrict__ W1,
    const float* __restrict__ b1, const float* __restrict__ b2,
    float* __restrict__ q) {
  int b = blockIdx.x;
  int u = threadIdx.x;
  const float* dr = dh + b * ND;
  float a0 = 0.f, a1 = 0.f, a2 = 0.f, a3 = 0.f;
  for (int k = 0; k < ND; k += 4) {
    a0 = fmaf(dr[k + 0], W1[(size_t)(k + 0) * NU + u], a0);
    a1 = fmaf(dr[k + 1], W1[(size_t)(k + 1) * NU + u], a1);
    a2 = fmaf(dr[k + 2], W1[(size_t)(k + 2) * NU + u], a2);
    a3 = fmaf(dr[k + 3], W1[(size_t)(k + 3) * NU + u], a3);
  }
  q[b * NU + u] = b1[u] + b2[u] + ((a0 + a1) + (a2 + a3));
}

// ---------------- K0b: pack W2 -> bf16 32x32x16 B-fragment order ----------------
// frag-lane tid: lane=tid&63, ntg=(tid>>6)&15, ks=tid>>10 (32 K-steps of 16)
// element j: col = ntg*32 + (lane&31), k = ks*16 + (lane>>5)*8 + j
__global__ __launch_bounds__(256) void packW2_kernel(
    const float* __restrict__ W2, unsigned short* __restrict__ w2p) {
  int tid = blockIdx.x * 256 + threadIdx.x;  // 0..32767
  int lane = tid & 63;
  int ntg = (tid >> 6) & 15;
  int ks = tid >> 10;
  int col = ntg * 32 + (lane & 31);
  int k0 = ks * 16 + ((lane >> 5) << 3);
  const float* src = W2 + (size_t)k0 * NU + col;
  ushort4 lo, hi;
  lo.x = f2bf(src[0 * NU]); lo.y = f2bf(src[1 * NU]);
  lo.z = f2bf(src[2 * NU]); lo.w = f2bf(src[3 * NU]);
  hi.x = f2bf(src[4 * NU]); hi.y = f2bf(src[5 * NU]);
  hi.z = f2bf(src[6 * NU]); hi.w = f2bf(src[7 * NU]);
  ushort4* dst = (ushort4*)(w2p + (size_t)tid * 8);
  dst[0] = lo; dst[1] = hi;
}

// ---------------- K2: fused logits = tanh(q + enc@W2) @ V  (bV softmax-invariant)
// EXACT R4-desync structure (clean counters: WRITE 512KB, no spill, 158us) with ONE
// verified fix: bijective LDS swizzle (row&31)<<4 instead of (row&7)<<4.
// R4's 4-way ds_read conflict (SQ_LDS_BANK_CONFLICT 4.19M) -> ~0 (residual 2-way
// aliasing is free per m136). Everything else byte-identical to the 158us kernel.
__global__ __launch_bounds__(512, 4) void logits_kernel(
    const float* __restrict__ enc, const unsigned short* __restrict__ w2p,
    const float* __restrict__ q, const float* __restrict__ Vw,
    float* __restrict__ logits) {
  __shared__ unsigned short encA[64 * 512];   // 64KB bf16, bijective-swizzled rows
  __shared__ float red[8][64];

  const int tid = threadIdx.x;
  const int wave = tid >> 6;
  const int lane = tid & 63;
  const int wg = blockIdx.x;
  const int b = wg >> 5;
  const int tch = wg & 31;
  const char* w2pc = (const char*)w2p;

  // per-wave K rotation: phase i handles ks = (rot + i) & 31
  const int rot = wave * 4;
  // byte offset of this wave's B fragment pair within one ks block (16KB)
  const int bsub = ((2 * wave) * 64 + lane) * 16;   // < 16384

  // prologue B loads (phases rot, rot+1): in flight during staging
  int voffB = rot * 16384 + bsub;
  bf16x8 b0a = *(const bf16x8*)(w2pc + voffB);
  bf16x8 b0b = *(const bf16x8*)(w2pc + voffB + 1024);
  voffB = (voffB + 16384) & 0x7FFFF;
  bf16x8 b1a = *(const bf16x8*)(w2pc + voffB);
  bf16x8 b1b = *(const bf16x8*)(w2pc + voffB + 1024);
  voffB = (voffB + 16384) & 0x7FFFF;   // now points at phase rot+2

  // stage enc tile [64 rows x 512] f32 -> bf16 LDS; swizzle ^((row&31)<<4) [bijective]
  const float4* encBase = (const float4*)(enc + ((size_t)b * NT + (size_t)tch * 64) * ND);
#pragma unroll
  for (int i = 0; i < 8; ++i) {
    int idx8 = i * 512 + tid;   // float8 index; 64 per row
    int row = idx8 >> 6;
    int c8 = idx8 & 63;
    float4 v0 = encBase[idx8 * 2];
    float4 v1 = encBase[idx8 * 2 + 1];
    unsigned int p0, p1, p2, p3;
    asm("v_cvt_pk_bf16_f32 %0, %1, %2" : "=v"(p0) : "v"(v0.x), "v"(v0.y));
    asm("v_cvt_pk_bf16_f32 %0, %1, %2" : "=v"(p1) : "v"(v0.z), "v"(v0.w));
    asm("v_cvt_pk_bf16_f32 %0, %1, %2" : "=v"(p2) : "v"(v1.x), "v"(v1.y));
    asm("v_cvt_pk_bf16_f32 %0, %1, %2" : "=v"(p3) : "v"(v1.z), "v"(v1.w));
    uint4 pk; pk.x = p0; pk.y = p1; pk.z = p2; pk.w = p3;
    int byteoff = row * 1024 + ((c8 * 16) ^ ((row & 31) << 4));
    *(uint4*)((char*)encA + byteoff) = pk;
  }

  f32x16 acc00 = {}, acc01 = {}, acc10 = {}, acc11 = {};

  // A addressing: row = amt*32 + (lane&31); col byte = (ks*32 + kfix) ^ aswz
  const int arow0 = (lane & 31) * 1024;
  const int arow1 = arow0 + 32 * 1024;
  const int aswz = (lane & 31) << 4;       // bijective: (row&31)<<4, same for both tiles
  const int kfix = (lane >> 5) << 4;
  int kaBase = rot * 32 + kfix;            // wraps in [0,1024)
  const char* encAc = (const char*)encA;

  __syncthreads();

#pragma unroll
  for (int i = 0; i < 32; i += 2) {
    // even phase: consume b0, refill slot for phase i+2 (wraps harmlessly at end)
    int ka = kaBase ^ aswz;
    kaBase = (kaBase + 32) & 1023;
    bf16x8 a0 = *(const bf16x8*)(encAc + arow0 + ka);
    bf16x8 a1 = *(const bf16x8*)(encAc + arow1 + ka);
    bf16x8 n0a = *(const bf16x8*)(w2pc + voffB);
    bf16x8 n0b = *(const bf16x8*)(w2pc + voffB + 1024);
    voffB = (voffB + 16384) & 0x7FFFF;
    __builtin_amdgcn_s_setprio(1);
    acc00 = __builtin_amdgcn_mfma_f32_32x32x16_bf16(a0, b0a, acc00, 0, 0, 0);
    acc01 = __builtin_amdgcn_mfma_f32_32x32x16_bf16(a0, b0b, acc01, 0, 0, 0);
    acc10 = __builtin_amdgcn_mfma_f32_32x32x16_bf16(a1, b0a, acc10, 0, 0, 0);
    acc11 = __builtin_amdgcn_mfma_f32_32x32x16_bf16(a1, b0b, acc11, 0, 0, 0);
    __builtin_amdgcn_s_setprio(0);
    b0a = n0a; b0b = n0b;

    // odd phase: consume b1, refill slot for phase i+3
    int kb = kaBase ^ aswz;
    kaBase = (kaBase + 32) & 1023;
    bf16x8 a2 = *(const bf16x8*)(encAc + arow0 + kb);
    bf16x8 a3 = *(const bf16x8*)(encAc + arow1 + kb);
    bf16x8 n1a = *(const bf16x8*)(w2pc + voffB);
    bf16x8 n1b = *(const bf16x8*)(w2pc + voffB + 1024);
    voffB = (voffB + 16384) & 0x7FFFF;
    __builtin_amdgcn_s_setprio(1);
    acc00 = __builtin_amdgcn_mfma_f32_32x32x16_bf16(a2, b1a, acc00, 0, 0, 0);
    acc01 = __builtin_amdgcn_mfma_f32_32x32x16_bf16(a2, b1b, acc01, 0, 0, 0);
    acc10 = __builtin_amdgcn_mfma_f32_32x32x16_bf16(a3, b1a, acc10, 0, 0, 0);
    acc11 = __builtin_amdgcn_mfma_f32_32x32x16_bf16(a3, b1b, acc11, 0, 0, 0);
    __builtin_amdgcn_s_setprio(0);
    b1a = n1a; b1b = n1b;
  }

  // epilogue: logit[row] = sum_col tanh(acc + q[col]) * V[col]
  // 32x32 D layout (m74/m101): col = lane&31, row = (reg&3) + 8*(reg>>2) + 4*(lane>>5)
  const int col = lane & 31;
  const float qv0 = q[b * NU + wave * 64 + col];
  const float qv1 = q[b * NU + wave * 64 + 32 + col];
  const float Vv0 = Vw[wave * 64 + col];
  const float Vv1 = Vw[wave * 64 + 32 + col];
  const int hi4 = (lane >> 5) << 2;

#pragma unroll
  for (int amt = 0; amt < 2; ++amt) {
#pragma unroll
    for (int reg = 0; reg < 16; ++reg) {
      float c0 = amt ? acc10[reg] : acc00[reg];
      float c1 = amt ? acc11[reg] : acc01[reg];
      float s = fast_tanh(c0 + qv0) * Vv0 + fast_tanh(c1 + qv1) * Vv1;
      s += __shfl_xor(s, 1);
      s += __shfl_xor(s, 2);
      s += __shfl_xor(s, 4);
      s += __shfl_xor(s, 8);
      s += __shfl_xor(s, 16);
      if (col == 0) {
        int row = (reg & 3) + ((reg >> 2) << 3) + hi4;
        red[wave][amt * 32 + row] = s;
      }
    }
  }
  __syncthreads();
  if (tid < 64) {
    float t = 0.f;
#pragma unroll
    for (int w = 0; w < 8; ++w) t += red[w][tid];
    logits[(size_t)b * NT + (size_t)tch * 64 + tid] = t;
  }
}

// ---------------- K3: in-place softmax over T per batch ----------------
__global__ __launch_bounds__(512) void softmax_kernel(float* __restrict__ wts) {
  int b = blockIdx.x;
  int tid = threadIdx.x;
  float4* base = (float4*)(wts + (size_t)b * NT);
  float4 v = base[tid];
  float m = fmaxf(fmaxf(v.x, v.y), fmaxf(v.z, v.w));
#pragma unroll
  for (int d = 1; d < 64; d <<= 1) m = fmaxf(m, __shfl_xor(m, d));
  __shared__ float sm[8];
  __shared__ float ss[8];
  int w = tid >> 6;
  if ((tid & 63) == 0) sm[w] = m;
  __syncthreads();
  float M = sm[0];
#pragma unroll
  for (int i = 1; i < 8; ++i) M = fmaxf(M, sm[i]);
  float e0 = __expf(v.x - M), e1 = __expf(v.y - M), e2 = __expf(v.z - M), e3 = __expf(v.w - M);
  float s = e0 + e1 + e2 + e3;
#pragma unroll
  for (int d = 1; d < 64; d <<= 1) s += __shfl_xor(s, d);
  if ((tid & 63) == 0) ss[w] = s;
  __syncthreads();
  float S = 0.f;
#pragma unroll
  for (int i = 0; i < 8; ++i) S += ss[i];
  float inv = 1.0f / S;
  base[tid] = (float4){e0 * inv, e1 * inv, e2 * inv, e3 * inv};
}

// ---------------- K4: context partials over t-slices (f32, coalesced) ----------------
__global__ __launch_bounds__(512) void ctx_partial_kernel(
    const float* __restrict__ enc, const float* __restrict__ wts,
    float* __restrict__ partials) {
  int bx = blockIdx.x;          // b*16 + slice
  int b = bx >> 4;
  int slice = bx & 15;
  int tid = threadIdx.x;        // d index
  const float* e = enc + ((size_t)b * NT + (size_t)slice * 128) * ND + tid;
  const float* wp = wts + (size_t)b * NT + slice * 128;
  float acc = 0.0f;
#pragma unroll 4
  for (int tt = 0; tt < 128; ++tt) {
    acc = fmaf(wp[tt], e[(size_t)tt * ND], acc);
  }
  partials[(size_t)bx * ND + tid] = acc;
}

__global__ __launch_bounds__(512) void ctx_combine_kernel(
    const float* __restrict__ partials, float* __restrict__ ctx) {
  int b = blockIdx.x;
  int tid = threadIdx.x;
  float s = 0.0f;
#pragma unroll
  for (int i = 0; i < 16; ++i) s += partials[((size_t)b * 16 + i) * ND + tid];
  ctx[(size_t)b * ND + tid] = s;
}

// ---------------- launch ----------------
extern "C" void kernel_launch(void* const* d_in, const int* in_sizes, int n_in,
                              void* d_out, int out_size, void* d_ws, size_t ws_size,
                              hipStream_t stream) {
  const float* dh  = (const float*)d_in[0];
  const float* enc = (const float*)d_in[1];
  const float* W1  = (const float*)d_in[2];
  const float* b1  = (const float*)d_in[3];
  const float* W2  = (const float*)d_in[4];
  const float* b2  = (const float*)d_in[5];
  const float* Vw  = (const float*)d_in[6];
  // d_in[7] = bV: softmax is shift-invariant and logits are not an output -> unused

  // workspace layout
  float* q            = (float*)d_ws;                                  // 128KB
  unsigned short* w2p = (unsigned short*)((char*)d_ws + 131072);       // 512KB packed bf16
  float* partials     = (float*)((char*)d_ws + 655360);                // 2MB

  float* ctx = (float*)d_out;                 // [64,512]
  float* wts = (float*)d_out + NB * ND;       // [64,2048] (logits, then softmaxed in place)

  qproj_kernel<<<NB, 512, 0, stream>>>(dh, W1, b1, b2, q);
  packW2_kernel<<<128, 256, 0, stream>>>(W2, w2p);
  logits_kernel<<<NB * (NT / 64), 512, 0, stream>>>(enc, w2p, q, Vw, wts);
  softmax_kernel<<<NB, 512, 0, stream>>>(wts);
  ctx_partial_kernel<<<NB * 16, 512, 0, stream>>>(enc, wts, partials);
  ctx_combine_kernel<<<NB, 512, 0, stream>>>(partials, ctx);
}